// Round 18
// baseline (2223.573 us; speedup 1.0000x reference)
//
#include <hip/hip_runtime.h>
#include <math.h>

namespace {
constexpr int kV = 12001;
constexpr int kE = 300;
constexpr int kEp = 320;
constexpr int kR = 1024;
constexpr int kH = 512;
constexpr int kF = 2048;
constexpr int kB = 64;
constexpr int kT = 20;
constexpr int kL = 196;
constexpr int kNcat = 5 * kR + kH;   // 5632
constexpr int kKS = 4;
constexpr int kNc2 = kH + kF;        // 2560
constexpr int kProd = 44 * kKS;      // 176 producer blocks
}

typedef __attribute__((ext_vector_type(8))) short short8;
typedef __attribute__((ext_vector_type(4))) float f32x4;

#define GLB_PTR(p) ((const __attribute__((address_space(1))) void*)(p))
#define LDS_PTR(p) ((__attribute__((address_space(3))) void*)(p))

__device__ __forceinline__ unsigned short f2bf(float f) {
    unsigned u = __builtin_bit_cast(unsigned, f);
    u = (u + 0x7fffu + ((u >> 16) & 1u)) >> 16;
    return (unsigned short)u;
}
__device__ __forceinline__ float bf2f(unsigned short h) {
    unsigned u = ((unsigned)h) << 16;
    return __builtin_bit_cast(float, u);
}
__device__ __forceinline__ float fast_tanh(float x) {
    x = fminf(15.f, fmaxf(-15.f, x));
    const float e = __expf(2.f * x);
    return (e - 1.f) / (e + 1.f);
}
__device__ __forceinline__ float fast_sig(float x) {
    return 1.f / (1.f + __expf(-x));
}

__device__ __forceinline__ int xcd_swizzle(int orig, int nwg) {
    const int q = nwg >> 3, r = nwg & 7;
    const int xcd = orig & 7, lo = orig >> 3;
    return (xcd < r ? xcd * (q + 1) : r * (q + 1) + (xcd - r) * q) + lo;
}

// ---------------------------------------------------------------------------
// One-shot conversion/pack/zero kernel (+ step-counter zeroing).
// ---------------------------------------------------------------------------
__global__ __launch_bounds__(256)
void conv_all_kernel(const float* __restrict__ af_in,  unsigned short* __restrict__ af_out,
                     const float* __restrict__ ctx_in,
                     const float* __restrict__ lg_in,  unsigned short* __restrict__ lg_out,
                     const float* __restrict__ h2h_in, unsigned short* __restrict__ h2h_out,
                     const float* __restrict__ h2a_in, unsigned short* __restrict__ h2a_out,
                     const float* __restrict__ a2c_in, unsigned short* __restrict__ wcomb_out,
                     const float* __restrict__ emb_in, unsigned short* __restrict__ emb_out,
                     const float* __restrict__ i2h_in, unsigned short* __restrict__ i2h_out,
                     unsigned short* __restrict__ hz_out, float* __restrict__ cb_out,
                     const float* __restrict__ ctxb_in, const float* __restrict__ a2cb_in,
                     float* __restrict__ biasc_out, unsigned* __restrict__ cnt_out)
{
    constexpr int c0 = kB * kL * kF / 4;
    constexpr int c1 = c0 + kH * kF / 4;
    constexpr int c2 = c1 + kV * kR / 4;
    constexpr int c3 = c2 + 5 * kR * kR / 4;
    constexpr int c4 = c3 + kH * kR / 4;
    constexpr int c5 = c4 + 2 * kR * kF / 4;
    constexpr int c6 = c5 + kV * 80;
    constexpr int c7 = c6 + 5 * kR * 80;
    constexpr int c8 = c7 + kB * kR / 4;
    constexpr int c9 = c8 + kB * kR / 4;
    constexpr int c10 = c9 + kNc2 / 4;
    constexpr int c11 = c10 + 8;            // 32 uints of counters (zero)

    for (int i = blockIdx.x * 256 + threadIdx.x; i < c11; i += gridDim.x * 256) {
        if (i < c4) {
            const float* in; unsigned short* out; int l;
            if      (i < c0) { in = af_in;  out = af_out;    l = i; }
            else if (i < c1) { in = ctx_in; out = wcomb_out; l = i - c0; }
            else if (i < c2) { in = lg_in;  out = lg_out;    l = i - c1; }
            else if (i < c3) { in = h2h_in; out = h2h_out;   l = i - c2; }
            else             { in = h2a_in; out = h2a_out;   l = i - c3; }
            const float4 v = ((const float4*)in)[l];
            ushort4 o;
            o.x = f2bf(v.x); o.y = f2bf(v.y); o.z = f2bf(v.z); o.w = f2bf(v.w);
            ((ushort4*)out)[l] = o;
        } else if (i < c5) {
            const int l = i - c4;
            const int q = l >> 9;
            const int g = l & 511;
            const int irow = (q < kR) ? (kH + 2 * q) : (kH + 2 * (q - kR) + 1);
            const float4 v = ((const float4*)a2c_in)[l];
            ushort4 o;
            o.x = f2bf(v.x); o.y = f2bf(v.y); o.z = f2bf(v.z); o.w = f2bf(v.w);
            ((ushort4*)wcomb_out)[(size_t)irow * (kF / 4) + g] = o;
        } else if (i < c7) {
            const float* in; unsigned short* out; int l;
            if (i < c6) { in = emb_in; out = emb_out; l = i - c5; }
            else        { in = i2h_in; out = i2h_out; l = i - c6; }
            const int row = l / 80, c = l - row * 80;
            ushort4 o = make_ushort4(0, 0, 0, 0);
            if (c < 75) {
                const float4 v = *(const float4*)(in + (size_t)row * kE + c * 4);
                o.x = f2bf(v.x); o.y = f2bf(v.y); o.z = f2bf(v.z); o.w = f2bf(v.w);
            }
            *(ushort4*)(out + (size_t)row * kEp + c * 4) = o;
        } else if (i < c8) {
            ((ushort4*)hz_out)[i - c7] = make_ushort4(0, 0, 0, 0);
        } else if (i < c9) {
            ((float4*)cb_out)[i - c8] = make_float4(0.f, 0.f, 0.f, 0.f);
        } else if (i < c10) {
            const int l = i - c9;
            float4 v;
            if (l < kH / 4) {
                v = ((const float4*)ctxb_in)[l];
            } else {
                const int j0 = (l - kH / 4) * 4;
                float t[4];
                #pragma unroll
                for (int p = 0; p < 4; ++p) {
                    const int j = j0 + p;
                    const int r = j >> 1;
                    t[p] = a2cb_in[(j & 1) * kR + r];
                }
                v = make_float4(t[0], t[1], t[2], t[3]);
            }
            ((float4*)biasc_out)[l] = v;
        } else {
            ((uint4*)cnt_out)[i - c10] = make_uint4(0u, 0u, 0u, 0u);
        }
    }
}

// ---------------------------------------------------------------------------
// Pure-bf16 MFMA GEMM, width-16 global_load_lds staging, XCD-swizzled 1D grid.
// ---------------------------------------------------------------------------
template<bool OUT_BF16, bool GATHER>
__global__ __launch_bounds__(256)
void gemm_glds_kernel(const unsigned short* __restrict__ Ah, int lda,
                      const unsigned short* __restrict__ Wh, int ldw,
                      const float* __restrict__ bias,
                      void* __restrict__ Cp, int ldc,
                      int M, int N, int K,
                      const int* __restrict__ ridx,
                      int nbx, int nby, int nfirst)
{
    __shared__ __align__(16) unsigned short sA[128 * 32];
    __shared__ __align__(16) unsigned short sW[128 * 32];
    const int tid = threadIdx.x;
    const int swz = xcd_swizzle(blockIdx.x, nbx * nby);
    int bx, by;
    if (nfirst) { bx = swz % nbx; by = swz / nbx; }
    else        { by = swz % nby; bx = swz / nby; }
    const int m0 = by * 128;
    const int n0 = bx * 128;
    const int wave = tid >> 6, lane = tid & 63;
    const int wm = wave >> 1, wn = wave & 1;
    const int lrow = lane & 15, lkg = lane >> 4;

    const int rsub   = lane >> 2;
    const int cchunk = (lane & 3) * 8;

    f32x4 acc[4][4];
    #pragma unroll
    for (int mi = 0; mi < 4; ++mi)
        #pragma unroll
        for (int ni = 0; ni < 4; ++ni)
            acc[mi][ni] = (f32x4){0.f, 0.f, 0.f, 0.f};

    for (int k0 = 0; k0 < K; k0 += 32) {
        #pragma unroll
        for (int j = 0; j < 2; ++j) {
            const int mrow = m0 + wave * 32 + j * 16 + rsub;
            const int row = GATHER ? ridx[mrow] : mrow;
            __builtin_amdgcn_global_load_lds(
                GLB_PTR(Ah + (size_t)row * lda + k0 + cchunk),
                LDS_PTR(sA + wave * 1024 + j * 512), 16, 0, 0);
        }
        #pragma unroll
        for (int j = 0; j < 2; ++j) {
            const int n = n0 + wave * 32 + j * 16 + rsub;
            __builtin_amdgcn_global_load_lds(
                GLB_PTR(Wh + (size_t)n * ldw + k0 + cchunk),
                LDS_PTR(sW + wave * 1024 + j * 512), 16, 0, 0);
        }
        __syncthreads();

        short8 af[4], wf[4];
        #pragma unroll
        for (int mi = 0; mi < 4; ++mi)
            af[mi] = *(const short8*)(sA + (wm * 64 + mi * 16 + lrow) * 32 + lkg * 8);
        #pragma unroll
        for (int ni = 0; ni < 4; ++ni)
            wf[ni] = *(const short8*)(sW + (wn * 64 + ni * 16 + lrow) * 32 + lkg * 8);
        #pragma unroll
        for (int mi = 0; mi < 4; ++mi)
            #pragma unroll
            for (int ni = 0; ni < 4; ++ni)
                acc[mi][ni] = __builtin_amdgcn_mfma_f32_16x16x32_bf16(af[mi], wf[ni], acc[mi][ni], 0, 0, 0);
        __syncthreads();
    }

    #pragma unroll
    for (int mi = 0; mi < 4; ++mi) {
        const int mbase = m0 + wm * 64 + mi * 16 + lkg * 4;
        #pragma unroll
        for (int ni = 0; ni < 4; ++ni) {
            const int n = n0 + wn * 64 + ni * 16 + lrow;
            if (n >= N) continue;
            const float bb = bias ? bias[n] : 0.f;
            #pragma unroll
            for (int r = 0; r < 4; ++r) {
                const int m = mbase + r;
                const float v = acc[mi][ni][r] + bb;
                if (OUT_BF16) ((unsigned short*)Cp)[(size_t)m * ldc + n] = f2bf(v);
                else          ((float*)Cp)[(size_t)m * ldc + n] = v;
            }
        }
    }
}

// ---------------------------------------------------------------------------
// Fused per-step kernel (512 thr, 432 blocks):
//  blocks [0,176): producers — two 256-thr halves, each a gemm_sums instance
//    part[ks][64][kNcat] = h_prev @ [h2h | h2att].T slice; then release cnt[t].
//  blocks [176,432): consumers — spin on cnt[t]==176, acquire, att_step body.
// ---------------------------------------------------------------------------
__global__ __launch_bounds__(512)
void step_fused_kernel(const unsigned short* __restrict__ h_prev, int lda_h,
                       const unsigned short* __restrict__ wcat_bf,
                       float* __restrict__ part56,
                       const float* __restrict__ h2att_b,
                       const unsigned short* __restrict__ comb_bf,
                       const float* __restrict__ alpha_w,
                       const unsigned short* __restrict__ i2h_pre_bf,
                       const float* __restrict__ h2h_b,
                       float* __restrict__ cbuf,
                       unsigned short* __restrict__ h_all_bf,
                       unsigned* __restrict__ cnt,
                       int t)
{
    __shared__ union {
        struct { __align__(16) unsigned short sA[2][64 * 32]; __align__(16) unsigned short sW[2][64 * 32]; } p;
        struct { float ahT[8][64]; float awT[8][64]; float esm[kL]; float wsm[kL]; float red2[2]; } c;
    } sm;

    if (blockIdx.x < kProd) {
        // ---------------- producer ----------------
        const int half = threadIdx.x >> 8;
        const int tid = threadIdx.x & 255;
        const int bx = blockIdx.x % 44;
        const int ks = blockIdx.x / 44;
        const int n0 = bx * 128 + half * 64;
        const int kbeg = ks * (kR / kKS);
        const int wave = tid >> 6, lane = tid & 63;
        const int lrow = lane & 15, lkg = lane >> 4;
        const int rsub = lane >> 2;
        const int cchunk = (lane & 3) * 8;

        f32x4 acc[4];
        #pragma unroll
        for (int mi = 0; mi < 4; ++mi) acc[mi] = (f32x4){0.f, 0.f, 0.f, 0.f};

        unsigned short* sA = sm.p.sA[half];
        unsigned short* sW = sm.p.sW[half];

        for (int k0 = kbeg; k0 < kbeg + kR / kKS; k0 += 32) {
            __builtin_amdgcn_global_load_lds(
                GLB_PTR(h_prev + (size_t)(wave * 16 + rsub) * lda_h + k0 + cchunk),
                LDS_PTR(sA + wave * 512), 16, 0, 0);
            __builtin_amdgcn_global_load_lds(
                GLB_PTR(wcat_bf + (size_t)(n0 + wave * 16 + rsub) * kR + k0 + cchunk),
                LDS_PTR(sW + wave * 512), 16, 0, 0);
            __syncthreads();
            const short8 wf = *(const short8*)(sW + (wave * 16 + lrow) * 32 + lkg * 8);
            #pragma unroll
            for (int mi = 0; mi < 4; ++mi) {
                const short8 af = *(const short8*)(sA + (mi * 16 + lrow) * 32 + lkg * 8);
                acc[mi] = __builtin_amdgcn_mfma_f32_16x16x32_bf16(af, wf, acc[mi], 0, 0, 0);
            }
            __syncthreads();
        }

        float* po = part56 + (size_t)ks * 64 * kNcat;
        const int n = n0 + wave * 16 + lrow;
        #pragma unroll
        for (int mi = 0; mi < 4; ++mi)
            #pragma unroll
            for (int rr = 0; rr < 4; ++rr)
                po[(size_t)(mi * 16 + lkg * 4 + rr) * kNcat + n] = acc[mi][rr];

        __syncthreads();
        __threadfence();
        if (threadIdx.x == 0)
            __hip_atomic_fetch_add(cnt + t, 1u, __ATOMIC_RELEASE, __HIP_MEMORY_SCOPE_AGENT);
    } else {
        // ---------------- consumer ----------------
        const int cblk = blockIdx.x - kProd;
        const int fc = cblk >> 6, b = cblk & 63;
        const int tid = threadIdx.x;
        const int wave = tid >> 6, lane = tid & 63;

        if (tid == 0) {
            while (__hip_atomic_load(cnt + t, __ATOMIC_RELAXED, __HIP_MEMORY_SCOPE_AGENT) < (unsigned)kProd)
                __builtin_amdgcn_s_sleep(4);
            (void)__hip_atomic_load(cnt + t, __ATOMIC_ACQUIRE, __HIP_MEMORY_SCOPE_AGENT);
            __threadfence();
        }
        __syncthreads();

        if (tid < kH) {
            const size_t base = (size_t)b * kNcat + 5 * kR + tid;
            float v = h2att_b[tid];
            #pragma unroll
            for (int s = 0; s < kKS; ++s) v += part56[(size_t)s * 64 * kNcat + base];
            sm.c.ahT[tid & 7][tid >> 3] = v;
            sm.c.awT[tid & 7][tid >> 3] = alpha_w[tid];
        }
        __syncthreads();

        for (int l = wave; l < kL; l += 8) {
            const short8 pv = *(const short8*)(comb_bf + ((size_t)b * kL + l) * kNc2 + lane * 8);
            float a = 0.f;
            #pragma unroll
            for (int j = 0; j < 8; ++j)
                a += fast_tanh(bf2f(((const unsigned short*)&pv)[j]) + sm.c.ahT[j][lane]) * sm.c.awT[j][lane];
            #pragma unroll
            for (int off = 32; off; off >>= 1) a += __shfl_xor(a, off, 64);
            if (lane == 0) sm.c.esm[l] = a;
        }
        __syncthreads();

        if (wave == 0) {
            float m = -1e30f;
            for (int l = lane; l < kL; l += 64) m = fmaxf(m, sm.c.esm[l]);
            #pragma unroll
            for (int off = 32; off; off >>= 1) m = fmaxf(m, __shfl_xor(m, off, 64));
            float ssum = 0.f;
            for (int l = lane; l < kL; l += 64) ssum += __expf(sm.c.esm[l] - m);
            #pragma unroll
            for (int off = 32; off; off >>= 1) ssum += __shfl_xor(ssum, off, 64);
            if (lane == 0) { sm.c.red2[0] = m; sm.c.red2[1] = 1.f / ssum; }
        }
        __syncthreads();
        if (tid < kL) sm.c.wsm[tid] = __expf(sm.c.esm[tid] - sm.c.red2[0]) * sm.c.red2[1];
        __syncthreads();

        const int r = fc * 256 + (tid >> 1);
        const int l0 = (tid & 1) * 98;
        float s3 = 0.f, s4 = 0.f;
        const unsigned short* base = comb_bf + ((size_t)b * kL + l0) * kNc2 + kH + 2 * r;
        #pragma unroll 7
        for (int li = 0; li < 98; ++li) {
            const ushort2 v = *(const ushort2*)(base + (size_t)li * kNc2);
            const float wl = sm.c.wsm[l0 + li];
            s3 += wl * bf2f(v.x);
            s4 += wl * bf2f(v.y);
        }
        s3 += __shfl_xor(s3, 1, 64);
        s4 += __shfl_xor(s4, 1, 64);

        if ((tid & 1) == 0) {
            const unsigned short* ib = i2h_pre_bf + (size_t)(b * kT + t) * (5 * kR);
            float S0 = bf2f(ib[r])          + h2h_b[r];
            float S1 = bf2f(ib[kR + r])     + h2h_b[kR + r];
            float S2 = bf2f(ib[2 * kR + r]) + h2h_b[2 * kR + r];
            float S3 = bf2f(ib[3 * kR + r]) + h2h_b[3 * kR + r] + s3;
            float S4 = bf2f(ib[4 * kR + r]) + h2h_b[4 * kR + r] + s4;
            #pragma unroll
            for (int s = 0; s < kKS; ++s) {
                const float* p = part56 + (size_t)s * 64 * kNcat + (size_t)b * kNcat;
                S0 += p[r];
                S1 += p[kR + r];
                S2 += p[2 * kR + r];
                S3 += p[3 * kR + r];
                S4 += p[4 * kR + r];
            }

            const float ing = fast_sig(S0);
            const float fg  = fast_sig(S1);
            const float og  = fast_sig(S2);
            const float gg  = fmaxf(S3, S4);
            const int idx = b * kR + r;
            const float nc = fg * cbuf[idx] + ing * gg;
            const float nh = og * fast_tanh(nc);
            cbuf[idx] = nc;
            h_all_bf[(size_t)(b * kT + t) * kR + r] = f2bf(nh);
        }
    }
}

// ---------------------------------------------------------------------------
// in-place log_softmax over V; one block per row, 512 thr. Online max/sum.
// ---------------------------------------------------------------------------
__global__ __launch_bounds__(512)
void log_softmax_kernel(float* __restrict__ out)
{
    __shared__ float mred[512];
    __shared__ float sred[512];
    const int tid = threadIdx.x;
    float* row = out + (size_t)blockIdx.x * kV;

    float m = -1e30f, s = 0.f;
    for (int v = tid; v < kV; v += 512) {
        const float x = row[v];
        if (x > m) { s = s * __expf(m - x) + 1.f; m = x; }
        else        s += __expf(x - m);
    }
    mred[tid] = m; sred[tid] = s; __syncthreads();
    for (int st = 256; st > 0; st >>= 1) {
        if (tid < st) {
            const float m2 = mred[tid + st], s2 = sred[tid + st];
            const float M = fmaxf(mred[tid], m2);
            sred[tid] = sred[tid] * __expf(mred[tid] - M) + s2 * __expf(m2 - M);
            mred[tid] = M;
        }
        __syncthreads();
    }
    const float ls = mred[0] + logf(sred[0]);
    for (int v = tid; v < kV; v += 512) row[v] -= ls;
}

extern "C" void kernel_launch(void* const* d_in, const int* in_sizes, int n_in,
                              void* d_out, int out_size, void* d_ws, size_t ws_size,
                              hipStream_t stream)
{
    const int*   seq       = (const int*)  d_in[0];
    const float* att_feats = (const float*)d_in[1];
    const float* embed_w   = (const float*)d_in[2];
    const float* ctx2att_w = (const float*)d_in[3];
    const float* ctx2att_b = (const float*)d_in[4];
    const float* h2att_w   = (const float*)d_in[5];
    const float* h2att_b   = (const float*)d_in[6];
    const float* alpha_w   = (const float*)d_in[7];
    const float* i2h_w     = (const float*)d_in[9];
    const float* i2h_b     = (const float*)d_in[10];
    const float* h2h_w     = (const float*)d_in[11];
    const float* h2h_b     = (const float*)d_in[12];
    const float* a2c_w     = (const float*)d_in[13];
    const float* a2c_b     = (const float*)d_in[14];
    const float* logit_w   = (const float*)d_in[15];
    const float* logit_b   = (const float*)d_in[16];
    float* out = (float*)d_out;

    float* ws = (float*)d_ws;
    size_t off = 0;
    auto alloc = [&](size_t nf) { float* p = ws + off; off += (nf + 3) & ~(size_t)3; return p; };

    unsigned short* af_bf      = (unsigned short*)alloc((size_t)kB * kL * kF / 2);
    unsigned short* comb_bf    = (unsigned short*)alloc((size_t)kB * kL * kNc2 / 2);
    unsigned short* logit_hi   = (unsigned short*)alloc((size_t)kV * kR / 2);
    unsigned short* embed_bf   = (unsigned short*)alloc((size_t)kV * kEp / 2);
    unsigned short* i2h_bf     = (unsigned short*)alloc((size_t)5 * kR * kEp / 2);
    unsigned short* wcat_bf    = (unsigned short*)alloc((size_t)kNcat * kR / 2);
    unsigned short* wcomb_bf   = (unsigned short*)alloc((size_t)kNc2 * kF / 2);
    unsigned short* h_all_bf   = (unsigned short*)alloc((size_t)kB * kT * kR / 2);
    unsigned short* h_zero_bf  = (unsigned short*)alloc((size_t)kB * kR / 2);
    unsigned short* i2h_pre_bf = (unsigned short*)alloc((size_t)kB * kT * 5 * kR / 2);
    float* bias_comb = alloc((size_t)kNc2);
    float* part56    = alloc((size_t)kKS * kB * kNcat);
    float* cbuf      = alloc((size_t)kB * kR);
    unsigned* cnt    = (unsigned*)alloc(32);

    conv_all_kernel<<<4096, 256, 0, stream>>>(
        att_feats, af_bf, ctx2att_w, logit_w, logit_hi,
        h2h_w, wcat_bf, h2att_w, wcat_bf + (size_t)5 * kR * kR,
        a2c_w, wcomb_bf, embed_w, embed_bf, i2h_w, i2h_bf,
        h_zero_bf, cbuf, ctx2att_b, a2c_b, bias_comb, cnt);

    // comb = att_feats @ [ctx2att | a2c-interleaved].T + bias_comb -> bf16
    gemm_glds_kernel<true, false><<<dim3(20 * 98), 256, 0, stream>>>(
        af_bf, kF, wcomb_bf, kF, bias_comb, comb_bf, kNc2, kB * kL, kNc2, kF, nullptr,
        20, 98, 1);

    // i2h_pre = embed[seq] @ i2h_w.T + b -> bf16
    gemm_glds_kernel<true, true><<<dim3(40 * 10), 256, 0, stream>>>(
        embed_bf, kEp, i2h_bf, kEp, i2h_b, i2h_pre_bf, 5 * kR, kB * kT, 5 * kR, kEp, seq,
        40, 10, 1);

    // 20-step recurrence: ONE launch per step (producer/consumer fused)
    for (int t = 0; t < kT; ++t) {
        const unsigned short* h_prev = (t == 0) ? h_zero_bf : (h_all_bf + (size_t)(t - 1) * kR);
        const int lda_h = (t == 0) ? kR : kT * kR;
        step_fused_kernel<<<dim3(kProd + 4 * kB), 512, 0, stream>>>(
            h_prev, lda_h, wcat_bf, part56, h2att_b, comb_bf, alpha_w,
            i2h_pre_bf, h2h_b, cbuf, h_all_bf, cnt, t);
    }

    // logits = h_all @ logit_w.T + b -> out fp32
    gemm_glds_kernel<false, false><<<dim3(94 * 10), 256, 0, stream>>>(
        h_all_bf, kR, logit_hi, kR, logit_b, out, kV, kB * kT, kV, kR, nullptr,
        94, 10, 0);

    log_softmax_kernel<<<dim3(kB * kT), 512, 0, stream>>>(out);
}

// Round 19
// 1197.618 us; speedup vs baseline: 1.8567x; 1.8567x over previous
//
#include <hip/hip_runtime.h>
#include <math.h>

namespace {
constexpr int kV = 12001;
constexpr int kE = 300;
constexpr int kEp = 320;   // padded K for i2h
constexpr int kR = 1024;
constexpr int kH = 512;
constexpr int kF = 2048;
constexpr int kB = 64;
constexpr int kT = 20;
constexpr int kL = 196;
constexpr int kNcat = 5 * kR + kH;   // 5632: [h2h | h2att]
constexpr int kKS = 8;               // K-split for gemm_sums
constexpr int kNc2 = kH + kF;        // 2560: [p_att | itr-interleaved] cols
}

typedef __attribute__((ext_vector_type(8))) short short8;
typedef __attribute__((ext_vector_type(4))) float f32x4;

#define GLB_PTR(p) ((const __attribute__((address_space(1))) void*)(p))
#define LDS_PTR(p) ((__attribute__((address_space(3))) void*)(p))

__device__ __forceinline__ unsigned short f2bf(float f) {
    unsigned u = __builtin_bit_cast(unsigned, f);
    u = (u + 0x7fffu + ((u >> 16) & 1u)) >> 16;
    return (unsigned short)u;
}
__device__ __forceinline__ float bf2f(unsigned short h) {
    unsigned u = ((unsigned)h) << 16;
    return __builtin_bit_cast(float, u);
}
__device__ __forceinline__ float fast_tanh(float x) {
    x = fminf(15.f, fmaxf(-15.f, x));
    const float e = __expf(2.f * x);
    return (e - 1.f) / (e + 1.f);
}
__device__ __forceinline__ float fast_sig(float x) {
    return 1.f / (1.f + __expf(-x));
}

// bijective XCD-chunk swizzle (m204)
__device__ __forceinline__ int xcd_swizzle(int orig, int nwg) {
    const int q = nwg >> 3, r = nwg & 7;
    const int xcd = orig & 7, lo = orig >> 3;
    return (xcd < r ? xcd * (q + 1) : r * (q + 1) + (xcd - r) * q) + lo;
}

// ---------------------------------------------------------------------------
// One-shot conversion/pack/zero kernel.
// wcomb rows: 0-511 = ctx2att; 512+2r = a2c gate3 row r; 512+2r+1 = gate4 row r.
// ---------------------------------------------------------------------------
__global__ __launch_bounds__(256)
void conv_all_kernel(const float* __restrict__ af_in,  unsigned short* __restrict__ af_out,
                     const float* __restrict__ ctx_in,
                     const float* __restrict__ lg_in,  unsigned short* __restrict__ lg_out,
                     const float* __restrict__ h2h_in, unsigned short* __restrict__ h2h_out,
                     const float* __restrict__ h2a_in, unsigned short* __restrict__ h2a_out,
                     const float* __restrict__ a2c_in, unsigned short* __restrict__ wcomb_out,
                     const float* __restrict__ emb_in, unsigned short* __restrict__ emb_out,
                     const float* __restrict__ i2h_in, unsigned short* __restrict__ i2h_out,
                     unsigned short* __restrict__ hz_out, float* __restrict__ cb_out,
                     const float* __restrict__ ctxb_in, const float* __restrict__ a2cb_in,
                     float* __restrict__ biasc_out)
{
    constexpr int c0 = kB * kL * kF / 4;                 // af
    constexpr int c1 = c0 + kH * kF / 4;                 // ctx -> wcomb rows 0-511
    constexpr int c2 = c1 + kV * kR / 4;                 // logit
    constexpr int c3 = c2 + 5 * kR * kR / 4;             // h2h -> wcat
    constexpr int c4 = c3 + kH * kR / 4;                 // h2att -> wcat tail
    constexpr int c5 = c4 + 2 * kR * kF / 4;             // a2c -> wcomb interleaved
    constexpr int c6 = c5 + kV * 80;                     // embed pad
    constexpr int c7 = c6 + 5 * kR * 80;                 // i2h pad
    constexpr int c8 = c7 + kB * kR / 4;                 // h_zero
    constexpr int c9 = c8 + kB * kR / 4;                 // cbuf zero
    constexpr int c10 = c9 + kNc2 / 4;                   // bias_comb

    for (int i = blockIdx.x * 256 + threadIdx.x; i < c10; i += gridDim.x * 256) {
        if (i < c4) {
            const float* in; unsigned short* out; int l;
            if      (i < c0) { in = af_in;  out = af_out;    l = i; }
            else if (i < c1) { in = ctx_in; out = wcomb_out; l = i - c0; }
            else if (i < c2) { in = lg_in;  out = lg_out;    l = i - c1; }
            else if (i < c3) { in = h2h_in; out = h2h_out;   l = i - c2; }
            else             { in = h2a_in; out = h2a_out;   l = i - c3; }
            const float4 v = ((const float4*)in)[l];
            ushort4 o;
            o.x = f2bf(v.x); o.y = f2bf(v.y); o.z = f2bf(v.z); o.w = f2bf(v.w);
            ((ushort4*)out)[l] = o;
        } else if (i < c5) {
            // a2c row q -> wcomb row 512 + (q<kR ? 2q : 2(q-kR)+1)
            const int l = i - c4;
            const int q = l >> 9;                 // row (kF/4 = 512 groups)
            const int g = l & 511;                // col group
            const int irow = (q < kR) ? (kH + 2 * q) : (kH + 2 * (q - kR) + 1);
            const float4 v = ((const float4*)a2c_in)[l];
            ushort4 o;
            o.x = f2bf(v.x); o.y = f2bf(v.y); o.z = f2bf(v.z); o.w = f2bf(v.w);
            ((ushort4*)wcomb_out)[(size_t)irow * (kF / 4) + g] = o;
        } else if (i < c7) {
            const float* in; unsigned short* out; int l;
            if (i < c6) { in = emb_in; out = emb_out; l = i - c5; }
            else        { in = i2h_in; out = i2h_out; l = i - c6; }
            const int row = l / 80, c = l - row * 80;
            ushort4 o = make_ushort4(0, 0, 0, 0);
            if (c < 75) {
                const float4 v = *(const float4*)(in + (size_t)row * kE + c * 4);
                o.x = f2bf(v.x); o.y = f2bf(v.y); o.z = f2bf(v.z); o.w = f2bf(v.w);
            }
            *(ushort4*)(out + (size_t)row * kEp + c * 4) = o;
        } else if (i < c8) {
            ((ushort4*)hz_out)[i - c7] = make_ushort4(0, 0, 0, 0);
        } else if (i < c9) {
            ((float4*)cb_out)[i - c8] = make_float4(0.f, 0.f, 0.f, 0.f);
        } else {
            const int l = i - c9;   // float4 group of bias_comb (640 groups)
            float4 v;
            if (l < kH / 4) {
                v = ((const float4*)ctxb_in)[l];
            } else {
                const int j0 = (l - kH / 4) * 4;
                float t[4];
                #pragma unroll
                for (int p = 0; p < 4; ++p) {
                    const int j = j0 + p;
                    const int r = j >> 1;
                    t[p] = a2cb_in[(j & 1) * kR + r];
                }
                v = make_float4(t[0], t[1], t[2], t[3]);
            }
            ((float4*)biasc_out)[l] = v;
        }
    }
}

// ---------------------------------------------------------------------------
// Pure-bf16 MFMA GEMM, width-16 global_load_lds staging, XCD-swizzled 1D grid.
// ---------------------------------------------------------------------------
template<bool OUT_BF16, bool GATHER>
__global__ __launch_bounds__(256)
void gemm_glds_kernel(const unsigned short* __restrict__ Ah, int lda,
                      const unsigned short* __restrict__ Wh, int ldw,
                      const float* __restrict__ bias,
                      void* __restrict__ Cp, int ldc,
                      int M, int N, int K,
                      const int* __restrict__ ridx,
                      int nbx, int nby, int nfirst)
{
    __shared__ __align__(16) unsigned short sA[128 * 32];
    __shared__ __align__(16) unsigned short sW[128 * 32];
    const int tid = threadIdx.x;
    const int swz = xcd_swizzle(blockIdx.x, nbx * nby);
    int bx, by;
    if (nfirst) { bx = swz % nbx; by = swz / nbx; }
    else        { by = swz % nby; bx = swz / nby; }
    const int m0 = by * 128;
    const int n0 = bx * 128;
    const int wave = tid >> 6, lane = tid & 63;
    const int wm = wave >> 1, wn = wave & 1;
    const int lrow = lane & 15, lkg = lane >> 4;

    const int rsub   = lane >> 2;
    const int cchunk = (lane & 3) * 8;

    f32x4 acc[4][4];
    #pragma unroll
    for (int mi = 0; mi < 4; ++mi)
        #pragma unroll
        for (int ni = 0; ni < 4; ++ni)
            acc[mi][ni] = (f32x4){0.f, 0.f, 0.f, 0.f};

    for (int k0 = 0; k0 < K; k0 += 32) {
        #pragma unroll
        for (int j = 0; j < 2; ++j) {
            const int mrow = m0 + wave * 32 + j * 16 + rsub;
            const int row = GATHER ? ridx[mrow] : mrow;
            __builtin_amdgcn_global_load_lds(
                GLB_PTR(Ah + (size_t)row * lda + k0 + cchunk),
                LDS_PTR(sA + wave * 1024 + j * 512), 16, 0, 0);
        }
        #pragma unroll
        for (int j = 0; j < 2; ++j) {
            const int n = n0 + wave * 32 + j * 16 + rsub;
            __builtin_amdgcn_global_load_lds(
                GLB_PTR(Wh + (size_t)n * ldw + k0 + cchunk),
                LDS_PTR(sW + wave * 1024 + j * 512), 16, 0, 0);
        }
        __syncthreads();

        short8 af[4], wf[4];
        #pragma unroll
        for (int mi = 0; mi < 4; ++mi)
            af[mi] = *(const short8*)(sA + (wm * 64 + mi * 16 + lrow) * 32 + lkg * 8);
        #pragma unroll
        for (int ni = 0; ni < 4; ++ni)
            wf[ni] = *(const short8*)(sW + (wn * 64 + ni * 16 + lrow) * 32 + lkg * 8);
        #pragma unroll
        for (int mi = 0; mi < 4; ++mi)
            #pragma unroll
            for (int ni = 0; ni < 4; ++ni)
                acc[mi][ni] = __builtin_amdgcn_mfma_f32_16x16x32_bf16(af[mi], wf[ni], acc[mi][ni], 0, 0, 0);
        __syncthreads();
    }

    // epilogue: row = (lane>>4)*4 + reg, col = lane&15 (m89-verified layout)
    #pragma unroll
    for (int mi = 0; mi < 4; ++mi) {
        const int mbase = m0 + wm * 64 + mi * 16 + lkg * 4;
        #pragma unroll
        for (int ni = 0; ni < 4; ++ni) {
            const int n = n0 + wn * 64 + ni * 16 + lrow;
            if (n >= N) continue;
            const float bb = bias ? bias[n] : 0.f;
            #pragma unroll
            for (int r = 0; r < 4; ++r) {
                const int m = mbase + r;
                const float v = acc[mi][ni][r] + bb;
                if (OUT_BF16) ((unsigned short*)Cp)[(size_t)m * ldc + n] = f2bf(v);
                else          ((float*)Cp)[(size_t)m * ldc + n] = v;
            }
        }
    }
}

// ---------------------------------------------------------------------------
// Small-M sums GEMM with glds staging: part[ks][64][N] = A(64xK)@W(NxK).T
// grid (kNcat/64, kKS); Kblk = kR/kKS = 128 -> 4 serial k-iters.
// ---------------------------------------------------------------------------
__global__ __launch_bounds__(256)
void gemm_sums_kernel(const unsigned short* __restrict__ A, int lda,
                      const unsigned short* __restrict__ W, int ldw,
                      float* __restrict__ part, int N, int Kblk)
{
    __shared__ __align__(16) unsigned short sA[64 * 32];
    __shared__ __align__(16) unsigned short sW[64 * 32];
    const int tid = threadIdx.x;
    const int n0 = blockIdx.x * 64;
    const int ks = blockIdx.y;
    const int kbeg = ks * Kblk;
    const int wave = tid >> 6, lane = tid & 63;
    const int lrow = lane & 15, lkg = lane >> 4;
    const int rsub   = lane >> 2;
    const int cchunk = (lane & 3) * 8;

    f32x4 acc[4];
    #pragma unroll
    for (int mi = 0; mi < 4; ++mi) acc[mi] = (f32x4){0.f, 0.f, 0.f, 0.f};

    for (int k0 = kbeg; k0 < kbeg + Kblk; k0 += 32) {
        __builtin_amdgcn_global_load_lds(
            GLB_PTR(A + (size_t)(wave * 16 + rsub) * lda + k0 + cchunk),
            LDS_PTR(sA + wave * 512), 16, 0, 0);
        __builtin_amdgcn_global_load_lds(
            GLB_PTR(W + (size_t)(n0 + wave * 16 + rsub) * ldw + k0 + cchunk),
            LDS_PTR(sW + wave * 512), 16, 0, 0);
        __syncthreads();
        const short8 wf = *(const short8*)(sW + (wave * 16 + lrow) * 32 + lkg * 8);
        #pragma unroll
        for (int mi = 0; mi < 4; ++mi) {
            const short8 af = *(const short8*)(sA + (mi * 16 + lrow) * 32 + lkg * 8);
            acc[mi] = __builtin_amdgcn_mfma_f32_16x16x32_bf16(af, wf, acc[mi], 0, 0, 0);
        }
        __syncthreads();
    }

    float* po = part + (size_t)ks * 64 * N;
    const int n = n0 + wave * 16 + lrow;
    #pragma unroll
    for (int mi = 0; mi < 4; ++mi)
        #pragma unroll
        for (int rr = 0; rr < 4; ++rr)
            po[(size_t)(mi * 16 + lkg * 4 + rr) * N + n] = acc[mi][rr];
}

// ---------------------------------------------------------------------------
// Step kernel (512 thr): e + softmax + l-split INTERLEAVED readout + gates.
// grid (4 fc, 64 b). Thread pair (tid>>1) owns r; tid&1 = l-half.
// comb cols: 0-511 p_att; 512+2r = itr gate3 col r; 512+2r+1 = gate4 col r.
// ---------------------------------------------------------------------------
__global__ __launch_bounds__(512)
void att_step_kernel(const float* __restrict__ part56,
                     const float* __restrict__ h2att_b,
                     const unsigned short* __restrict__ comb_bf,
                     const float* __restrict__ alpha_w,
                     const unsigned short* __restrict__ i2h_pre_bf,
                     const float* __restrict__ h2h_b,
                     float* __restrict__ cbuf,
                     unsigned short* __restrict__ h_all_bf,
                     int t)
{
    const int fc = blockIdx.x, b = blockIdx.y;
    const int tid = threadIdx.x;
    const int wave = tid >> 6, lane = tid & 63;
    __shared__ float ahT[8][64];
    __shared__ float awT[8][64];
    __shared__ float esm[kL];
    __shared__ float wsm[kL];
    __shared__ float red2[2];

    if (tid < kH) {
        const size_t base = (size_t)b * kNcat + 5 * kR + tid;
        float v = h2att_b[tid];
        #pragma unroll
        for (int s = 0; s < kKS; ++s) v += part56[(size_t)s * 64 * kNcat + base];
        ahT[tid & 7][tid >> 3] = v;
        awT[tid & 7][tid >> 3] = alpha_w[tid];
    }
    __syncthreads();

    // e: 8 waves, wave handles l = wave, wave+8, ...
    for (int l = wave; l < kL; l += 8) {
        const short8 pv = *(const short8*)(comb_bf + ((size_t)b * kL + l) * kNc2 + lane * 8);
        float a = 0.f;
        #pragma unroll
        for (int j = 0; j < 8; ++j)
            a += fast_tanh(bf2f(((const unsigned short*)&pv)[j]) + ahT[j][lane]) * awT[j][lane];
        #pragma unroll
        for (int off = 32; off; off >>= 1) a += __shfl_xor(a, off, 64);
        if (lane == 0) esm[l] = a;
    }
    __syncthreads();

    if (wave == 0) {
        float m = -1e30f;
        for (int l = lane; l < kL; l += 64) m = fmaxf(m, esm[l]);
        #pragma unroll
        for (int off = 32; off; off >>= 1) m = fmaxf(m, __shfl_xor(m, off, 64));
        float ssum = 0.f;
        for (int l = lane; l < kL; l += 64) ssum += __expf(esm[l] - m);
        #pragma unroll
        for (int off = 32; off; off >>= 1) ssum += __shfl_xor(ssum, off, 64);
        if (lane == 0) { red2[0] = m; red2[1] = 1.f / ssum; }
    }
    __syncthreads();
    if (tid < kL) wsm[tid] = __expf(esm[tid] - red2[0]) * red2[1];
    __syncthreads();

    // l-split interleaved readout: one ushort2 per l = (gate3, gate4)
    const int r = fc * 256 + (tid >> 1);
    const int l0 = (tid & 1) * 98;
    float s3 = 0.f, s4 = 0.f;
    const unsigned short* base = comb_bf + ((size_t)b * kL + l0) * kNc2 + kH + 2 * r;
    #pragma unroll 7
    for (int li = 0; li < 98; ++li) {
        const ushort2 v = *(const ushort2*)(base + (size_t)li * kNc2);
        const float wl = wsm[l0 + li];
        s3 += wl * bf2f(v.x);
        s4 += wl * bf2f(v.y);
    }
    s3 += __shfl_xor(s3, 1, 64);
    s4 += __shfl_xor(s4, 1, 64);

    if ((tid & 1) == 0) {
        const unsigned short* ib = i2h_pre_bf + (size_t)(b * kT + t) * (5 * kR);
        float S0 = bf2f(ib[r])          + h2h_b[r];
        float S1 = bf2f(ib[kR + r])     + h2h_b[kR + r];
        float S2 = bf2f(ib[2 * kR + r]) + h2h_b[2 * kR + r];
        float S3 = bf2f(ib[3 * kR + r]) + h2h_b[3 * kR + r] + s3;
        float S4 = bf2f(ib[4 * kR + r]) + h2h_b[4 * kR + r] + s4;
        #pragma unroll
        for (int s = 0; s < kKS; ++s) {
            const float* p = part56 + (size_t)s * 64 * kNcat + (size_t)b * kNcat;
            S0 += p[r];
            S1 += p[kR + r];
            S2 += p[2 * kR + r];
            S3 += p[3 * kR + r];
            S4 += p[4 * kR + r];
        }

        const float ing = fast_sig(S0);
        const float fg  = fast_sig(S1);
        const float og  = fast_sig(S2);
        const float gg  = fmaxf(S3, S4);
        const int idx = b * kR + r;
        const float nc = fg * cbuf[idx] + ing * gg;
        const float nh = og * fast_tanh(nc);
        cbuf[idx] = nc;
        h_all_bf[(size_t)(b * kT + t) * kR + r] = f2bf(nh);
    }
}

// ---------------------------------------------------------------------------
// in-place log_softmax over V; one block per row, 512 thr, float4 loads.
// 12001 = 3000 float4 groups + 1 tail (handled by thread 0).
// ---------------------------------------------------------------------------
__global__ __launch_bounds__(512)
void log_softmax_kernel(float* __restrict__ out)
{
    __shared__ float mred[512];
    __shared__ float sred[512];
    const int tid = threadIdx.x;
    float* row = out + (size_t)blockIdx.x * kV;

    float m = -1e30f, s = 0.f;
    for (int g = tid; g < 3000; g += 512) {
        const float4 x4 = ((const float4*)row)[g];
        const float* x = (const float*)&x4;
        #pragma unroll
        for (int j = 0; j < 4; ++j) {
            const float x1 = x[j];
            if (x1 > m) { s = s * __expf(m - x1) + 1.f; m = x1; }
            else          s += __expf(x1 - m);
        }
    }
    if (tid == 0) {
        const float x1 = row[12000];
        if (x1 > m) { s = s * __expf(m - x1) + 1.f; m = x1; }
        else          s += __expf(x1 - m);
    }
    mred[tid] = m; sred[tid] = s; __syncthreads();
    for (int st = 256; st > 0; st >>= 1) {
        if (tid < st) {
            const float m2 = mred[tid + st], s2 = sred[tid + st];
            const float M = fmaxf(mred[tid], m2);
            sred[tid] = sred[tid] * __expf(mred[tid] - M) + s2 * __expf(m2 - M);
            mred[tid] = M;
        }
        __syncthreads();
    }
    const float ls = mred[0] + logf(sred[0]);
    for (int g = tid; g < 3000; g += 512) {
        float4 x4 = ((const float4*)row)[g];
        x4.x -= ls; x4.y -= ls; x4.z -= ls; x4.w -= ls;
        ((float4*)row)[g] = x4;
    }
    if (tid == 0) row[12000] -= ls;
}

extern "C" void kernel_launch(void* const* d_in, const int* in_sizes, int n_in,
                              void* d_out, int out_size, void* d_ws, size_t ws_size,
                              hipStream_t stream)
{
    const int*   seq       = (const int*)  d_in[0];
    const float* att_feats = (const float*)d_in[1];
    const float* embed_w   = (const float*)d_in[2];
    const float* ctx2att_w = (const float*)d_in[3];
    const float* ctx2att_b = (const float*)d_in[4];
    const float* h2att_w   = (const float*)d_in[5];
    const float* h2att_b   = (const float*)d_in[6];
    const float* alpha_w   = (const float*)d_in[7];
    const float* i2h_w     = (const float*)d_in[9];
    const float* i2h_b     = (const float*)d_in[10];
    const float* h2h_w     = (const float*)d_in[11];
    const float* h2h_b     = (const float*)d_in[12];
    const float* a2c_w     = (const float*)d_in[13];
    const float* a2c_b     = (const float*)d_in[14];
    const float* logit_w   = (const float*)d_in[15];
    const float* logit_b   = (const float*)d_in[16];
    float* out = (float*)d_out;

    float* ws = (float*)d_ws;
    size_t off = 0;
    auto alloc = [&](size_t nf) { float* p = ws + off; off += (nf + 3) & ~(size_t)3; return p; };

    unsigned short* af_bf      = (unsigned short*)alloc((size_t)kB * kL * kF / 2);   // 51 MB
    unsigned short* comb_bf    = (unsigned short*)alloc((size_t)kB * kL * kNc2 / 2); // 61.6 MB
    unsigned short* logit_hi   = (unsigned short*)alloc((size_t)kV * kR / 2);
    unsigned short* embed_bf   = (unsigned short*)alloc((size_t)kV * kEp / 2);
    unsigned short* i2h_bf     = (unsigned short*)alloc((size_t)5 * kR * kEp / 2);
    unsigned short* wcat_bf    = (unsigned short*)alloc((size_t)kNcat * kR / 2);     // 11.5 MB
    unsigned short* wcomb_bf   = (unsigned short*)alloc((size_t)kNc2 * kF / 2);      // 10.5 MB
    unsigned short* h_all_bf   = (unsigned short*)alloc((size_t)kB * kT * kR / 2);
    unsigned short* h_zero_bf  = (unsigned short*)alloc((size_t)kB * kR / 2);
    unsigned short* i2h_pre_bf = (unsigned short*)alloc((size_t)kB * kT * 5 * kR / 2); // 13 MB
    float* bias_comb = alloc((size_t)kNc2);
    float* part56    = alloc((size_t)kKS * kB * kNcat);  // 11.5 MB
    float* cbuf      = alloc((size_t)kB * kR);

    // all conversions + packs + zero-fills in ONE launch
    conv_all_kernel<<<4096, 256, 0, stream>>>(
        att_feats, af_bf, ctx2att_w, logit_w, logit_hi,
        h2h_w, wcat_bf, h2att_w, wcat_bf + (size_t)5 * kR * kR,
        a2c_w, wcomb_bf, embed_w, embed_bf, i2h_w, i2h_bf,
        h_zero_bf, cbuf, ctx2att_b, a2c_b, bias_comb);

    // comb = att_feats @ [ctx2att | a2c-interleaved].T + bias_comb -> bf16
    gemm_glds_kernel<true, false><<<dim3(20 * 98), 256, 0, stream>>>(
        af_bf, kF, wcomb_bf, kF, bias_comb, comb_bf, kNc2, kB * kL, kNc2, kF, nullptr,
        20, 98, 1);

    // i2h_pre = embed[seq] @ i2h_w.T + b -> bf16   (1280 x 5120, K=320 padded)
    gemm_glds_kernel<true, true><<<dim3(40 * 10), 256, 0, stream>>>(
        embed_bf, kEp, i2h_bf, kEp, i2h_b, i2h_pre_bf, 5 * kR, kB * kT, 5 * kR, kEp, seq,
        40, 10, 1);

    // 20-step recurrence: 2 launches per step
    for (int t = 0; t < kT; ++t) {
        const unsigned short* h_prev = (t == 0) ? h_zero_bf : (h_all_bf + (size_t)(t - 1) * kR);
        const int lda_h = (t == 0) ? kR : kT * kR;

        // part56 = h_prev @ [h2h | h2att].T   (64 x 5632, K=1024, ks=8)
        gemm_sums_kernel<<<dim3(kNcat / 64, kKS), 256, 0, stream>>>(
            h_prev, lda_h, wcat_bf, kR, part56, kNcat, kR / kKS);

        att_step_kernel<<<dim3(4, kB), 512, 0, stream>>>(
            part56, h2att_b, comb_bf, alpha_w, i2h_pre_bf, h2h_b,
            cbuf, h_all_bf, t);
    }

    // logits = h_all @ logit_w.T + b -> out fp32  (1280 x 12001, K=1024)
    gemm_glds_kernel<false, false><<<dim3(94 * 10), 256, 0, stream>>>(
        h_all_bf, kR, logit_hi, kR, logit_b, out, kV, kB * kT, kV, kR, nullptr,
        94, 10, 0);

    log_softmax_kernel<<<dim3(kB * kT), 512, 0, stream>>>(out);
}

// Round 20
// 1138.466 us; speedup vs baseline: 1.9531x; 1.0520x over previous
//
#include <hip/hip_runtime.h>
#include <math.h>

namespace {
constexpr int kV = 12001;
constexpr int kE = 300;
constexpr int kEp = 320;   // padded K for i2h
constexpr int kR = 1024;
constexpr int kH = 512;
constexpr int kF = 2048;
constexpr int kB = 64;
constexpr int kT = 20;
constexpr int kL = 196;
constexpr int kNcat = 5 * kR + kH;   // 5632: [h2h | h2att]
constexpr int kKS = 4;               // K-split for gemm_sums (R17-proven)
constexpr int kNc2 = kH + kF;        // 2560: [p_att | itr-interleaved] cols
}

typedef __attribute__((ext_vector_type(8))) short short8;
typedef __attribute__((ext_vector_type(4))) float f32x4;

#define GLB_PTR(p) ((const __attribute__((address_space(1))) void*)(p))
#define LDS_PTR(p) ((__attribute__((address_space(3))) void*)(p))

__device__ __forceinline__ unsigned short f2bf(float f) {
    unsigned u = __builtin_bit_cast(unsigned, f);
    u = (u + 0x7fffu + ((u >> 16) & 1u)) >> 16;
    return (unsigned short)u;
}
__device__ __forceinline__ float bf2f(unsigned short h) {
    unsigned u = ((unsigned)h) << 16;
    return __builtin_bit_cast(float, u);
}
__device__ __forceinline__ float fast_tanh(float x) {
    x = fminf(15.f, fmaxf(-15.f, x));
    const float e = __expf(2.f * x);
    return (e - 1.f) / (e + 1.f);
}
__device__ __forceinline__ float fast_sig(float x) {
    return 1.f / (1.f + __expf(-x));
}

// bijective XCD-chunk swizzle (m204)
__device__ __forceinline__ int xcd_swizzle(int orig, int nwg) {
    const int q = nwg >> 3, r = nwg & 7;
    const int xcd = orig & 7, lo = orig >> 3;
    return (xcd < r ? xcd * (q + 1) : r * (q + 1) + (xcd - r) * q) + lo;
}

// ---------------------------------------------------------------------------
// One-shot conversion/pack/zero kernel.
// wcomb rows: 0-511 = ctx2att; 512+2r = a2c gate3 row r; 512+2r+1 = gate4 row r.
// ---------------------------------------------------------------------------
__global__ __launch_bounds__(256)
void conv_all_kernel(const float* __restrict__ af_in,  unsigned short* __restrict__ af_out,
                     const float* __restrict__ ctx_in,
                     const float* __restrict__ lg_in,  unsigned short* __restrict__ lg_out,
                     const float* __restrict__ h2h_in, unsigned short* __restrict__ h2h_out,
                     const float* __restrict__ h2a_in, unsigned short* __restrict__ h2a_out,
                     const float* __restrict__ a2c_in, unsigned short* __restrict__ wcomb_out,
                     const float* __restrict__ emb_in, unsigned short* __restrict__ emb_out,
                     const float* __restrict__ i2h_in, unsigned short* __restrict__ i2h_out,
                     unsigned short* __restrict__ hz_out, float* __restrict__ cb_out,
                     const float* __restrict__ ctxb_in, const float* __restrict__ a2cb_in,
                     float* __restrict__ biasc_out)
{
    constexpr int c0 = kB * kL * kF / 4;                 // af
    constexpr int c1 = c0 + kH * kF / 4;                 // ctx -> wcomb rows 0-511
    constexpr int c2 = c1 + kV * kR / 4;                 // logit
    constexpr int c3 = c2 + 5 * kR * kR / 4;             // h2h -> wcat
    constexpr int c4 = c3 + kH * kR / 4;                 // h2att -> wcat tail
    constexpr int c5 = c4 + 2 * kR * kF / 4;             // a2c -> wcomb interleaved
    constexpr int c6 = c5 + kV * 80;                     // embed pad
    constexpr int c7 = c6 + 5 * kR * 80;                 // i2h pad
    constexpr int c8 = c7 + kB * kR / 4;                 // h_zero
    constexpr int c9 = c8 + kB * kR / 4;                 // cbuf zero
    constexpr int c10 = c9 + kNc2 / 4;                   // bias_comb

    for (int i = blockIdx.x * 256 + threadIdx.x; i < c10; i += gridDim.x * 256) {
        if (i < c4) {
            const float* in; unsigned short* out; int l;
            if      (i < c0) { in = af_in;  out = af_out;    l = i; }
            else if (i < c1) { in = ctx_in; out = wcomb_out; l = i - c0; }
            else if (i < c2) { in = lg_in;  out = lg_out;    l = i - c1; }
            else if (i < c3) { in = h2h_in; out = h2h_out;   l = i - c2; }
            else             { in = h2a_in; out = h2a_out;   l = i - c3; }
            const float4 v = ((const float4*)in)[l];
            ushort4 o;
            o.x = f2bf(v.x); o.y = f2bf(v.y); o.z = f2bf(v.z); o.w = f2bf(v.w);
            ((ushort4*)out)[l] = o;
        } else if (i < c5) {
            // a2c row q -> wcomb row 512 + (q<kR ? 2q : 2(q-kR)+1)
            const int l = i - c4;
            const int q = l >> 9;                 // row (kF/4 = 512 groups)
            const int g = l & 511;                // col group
            const int irow = (q < kR) ? (kH + 2 * q) : (kH + 2 * (q - kR) + 1);
            const float4 v = ((const float4*)a2c_in)[l];
            ushort4 o;
            o.x = f2bf(v.x); o.y = f2bf(v.y); o.z = f2bf(v.z); o.w = f2bf(v.w);
            ((ushort4*)wcomb_out)[(size_t)irow * (kF / 4) + g] = o;
        } else if (i < c7) {
            const float* in; unsigned short* out; int l;
            if (i < c6) { in = emb_in; out = emb_out; l = i - c5; }
            else        { in = i2h_in; out = i2h_out; l = i - c6; }
            const int row = l / 80, c = l - row * 80;
            ushort4 o = make_ushort4(0, 0, 0, 0);
            if (c < 75) {
                const float4 v = *(const float4*)(in + (size_t)row * kE + c * 4);
                o.x = f2bf(v.x); o.y = f2bf(v.y); o.z = f2bf(v.z); o.w = f2bf(v.w);
            }
            *(ushort4*)(out + (size_t)row * kEp + c * 4) = o;
        } else if (i < c8) {
            ((ushort4*)hz_out)[i - c7] = make_ushort4(0, 0, 0, 0);
        } else if (i < c9) {
            ((float4*)cb_out)[i - c8] = make_float4(0.f, 0.f, 0.f, 0.f);
        } else {
            const int l = i - c9;   // float4 group of bias_comb (640 groups)
            float4 v;
            if (l < kH / 4) {
                v = ((const float4*)ctxb_in)[l];
            } else {
                const int j0 = (l - kH / 4) * 4;
                float t[4];
                #pragma unroll
                for (int p = 0; p < 4; ++p) {
                    const int j = j0 + p;
                    const int r = j >> 1;
                    t[p] = a2cb_in[(j & 1) * kR + r];
                }
                v = make_float4(t[0], t[1], t[2], t[3]);
            }
            ((float4*)biasc_out)[l] = v;
        }
    }
}

// ---------------------------------------------------------------------------
// Pure-bf16 MFMA GEMM, width-16 global_load_lds staging, XCD-swizzled 1D grid.
// ---------------------------------------------------------------------------
template<bool OUT_BF16, bool GATHER>
__global__ __launch_bounds__(256)
void gemm_glds_kernel(const unsigned short* __restrict__ Ah, int lda,
                      const unsigned short* __restrict__ Wh, int ldw,
                      const float* __restrict__ bias,
                      void* __restrict__ Cp, int ldc,
                      int M, int N, int K,
                      const int* __restrict__ ridx,
                      int nbx, int nby, int nfirst)
{
    __shared__ __align__(16) unsigned short sA[128 * 32];
    __shared__ __align__(16) unsigned short sW[128 * 32];
    const int tid = threadIdx.x;
    const int swz = xcd_swizzle(blockIdx.x, nbx * nby);
    int bx, by;
    if (nfirst) { bx = swz % nbx; by = swz / nbx; }
    else        { by = swz % nby; bx = swz / nby; }
    const int m0 = by * 128;
    const int n0 = bx * 128;
    const int wave = tid >> 6, lane = tid & 63;
    const int wm = wave >> 1, wn = wave & 1;
    const int lrow = lane & 15, lkg = lane >> 4;

    const int rsub   = lane >> 2;
    const int cchunk = (lane & 3) * 8;

    f32x4 acc[4][4];
    #pragma unroll
    for (int mi = 0; mi < 4; ++mi)
        #pragma unroll
        for (int ni = 0; ni < 4; ++ni)
            acc[mi][ni] = (f32x4){0.f, 0.f, 0.f, 0.f};

    for (int k0 = 0; k0 < K; k0 += 32) {
        #pragma unroll
        for (int j = 0; j < 2; ++j) {
            const int mrow = m0 + wave * 32 + j * 16 + rsub;
            const int row = GATHER ? ridx[mrow] : mrow;
            __builtin_amdgcn_global_load_lds(
                GLB_PTR(Ah + (size_t)row * lda + k0 + cchunk),
                LDS_PTR(sA + wave * 1024 + j * 512), 16, 0, 0);
        }
        #pragma unroll
        for (int j = 0; j < 2; ++j) {
            const int n = n0 + wave * 32 + j * 16 + rsub;
            __builtin_amdgcn_global_load_lds(
                GLB_PTR(Wh + (size_t)n * ldw + k0 + cchunk),
                LDS_PTR(sW + wave * 1024 + j * 512), 16, 0, 0);
        }
        __syncthreads();

        short8 af[4], wf[4];
        #pragma unroll
        for (int mi = 0; mi < 4; ++mi)
            af[mi] = *(const short8*)(sA + (wm * 64 + mi * 16 + lrow) * 32 + lkg * 8);
        #pragma unroll
        for (int ni = 0; ni < 4; ++ni)
            wf[ni] = *(const short8*)(sW + (wn * 64 + ni * 16 + lrow) * 32 + lkg * 8);
        #pragma unroll
        for (int mi = 0; mi < 4; ++mi)
            #pragma unroll
            for (int ni = 0; ni < 4; ++ni)
                acc[mi][ni] = __builtin_amdgcn_mfma_f32_16x16x32_bf16(af[mi], wf[ni], acc[mi][ni], 0, 0, 0);
        __syncthreads();
    }

    // epilogue: row = (lane>>4)*4 + reg, col = lane&15 (m89-verified layout)
    #pragma unroll
    for (int mi = 0; mi < 4; ++mi) {
        const int mbase = m0 + wm * 64 + mi * 16 + lkg * 4;
        #pragma unroll
        for (int ni = 0; ni < 4; ++ni) {
            const int n = n0 + wn * 64 + ni * 16 + lrow;
            if (n >= N) continue;
            const float bb = bias ? bias[n] : 0.f;
            #pragma unroll
            for (int r = 0; r < 4; ++r) {
                const int m = mbase + r;
                const float v = acc[mi][ni][r] + bb;
                if (OUT_BF16) ((unsigned short*)Cp)[(size_t)m * ldc + n] = f2bf(v);
                else          ((float*)Cp)[(size_t)m * ldc + n] = v;
            }
        }
    }
}

// ---------------------------------------------------------------------------
// Small-M sums GEMM with glds staging: part[ks][64][N] = A(64xK)@W(NxK).T
// grid (kNcat/64, kKS); Kblk = kR/kKS = 256 -> 8 serial k-iters.
// ---------------------------------------------------------------------------
__global__ __launch_bounds__(256)
void gemm_sums_kernel(const unsigned short* __restrict__ A, int lda,
                      const unsigned short* __restrict__ W, int ldw,
                      float* __restrict__ part, int N, int Kblk)
{
    __shared__ __align__(16) unsigned short sA[64 * 32];
    __shared__ __align__(16) unsigned short sW[64 * 32];
    const int tid = threadIdx.x;
    const int n0 = blockIdx.x * 64;
    const int ks = blockIdx.y;
    const int kbeg = ks * Kblk;
    const int wave = tid >> 6, lane = tid & 63;
    const int lrow = lane & 15, lkg = lane >> 4;
    const int rsub   = lane >> 2;
    const int cchunk = (lane & 3) * 8;

    f32x4 acc[4];
    #pragma unroll
    for (int mi = 0; mi < 4; ++mi) acc[mi] = (f32x4){0.f, 0.f, 0.f, 0.f};

    for (int k0 = kbeg; k0 < kbeg + Kblk; k0 += 32) {
        __builtin_amdgcn_global_load_lds(
            GLB_PTR(A + (size_t)(wave * 16 + rsub) * lda + k0 + cchunk),
            LDS_PTR(sA + wave * 512), 16, 0, 0);
        __builtin_amdgcn_global_load_lds(
            GLB_PTR(W + (size_t)(n0 + wave * 16 + rsub) * ldw + k0 + cchunk),
            LDS_PTR(sW + wave * 512), 16, 0, 0);
        __syncthreads();
        const short8 wf = *(const short8*)(sW + (wave * 16 + lrow) * 32 + lkg * 8);
        #pragma unroll
        for (int mi = 0; mi < 4; ++mi) {
            const short8 af = *(const short8*)(sA + (mi * 16 + lrow) * 32 + lkg * 8);
            acc[mi] = __builtin_amdgcn_mfma_f32_16x16x32_bf16(af, wf, acc[mi], 0, 0, 0);
        }
        __syncthreads();
    }

    float* po = part + (size_t)ks * 64 * N;
    const int n = n0 + wave * 16 + lrow;
    #pragma unroll
    for (int mi = 0; mi < 4; ++mi)
        #pragma unroll
        for (int rr = 0; rr < 4; ++rr)
            po[(size_t)(mi * 16 + lkg * 4 + rr) * N + n] = acc[mi][rr];
}

// ---------------------------------------------------------------------------
// Step kernel (512 thr): e + softmax + l-split INTERLEAVED readout + gates.
// grid (64 b, 4 fc): same-b blocks are 64 apart in linear id -> SAME XCD
// (64 % 8 == 0), so the 4 fc-blocks share b's p_att slice in that L2.
// Thread pair (tid>>1) owns r; tid&1 = l-half.
// ---------------------------------------------------------------------------
__global__ __launch_bounds__(512)
void att_step_kernel(const float* __restrict__ part56,
                     const float* __restrict__ h2att_b,
                     const unsigned short* __restrict__ comb_bf,
                     const float* __restrict__ alpha_w,
                     const unsigned short* __restrict__ i2h_pre_bf,
                     const float* __restrict__ h2h_b,
                     float* __restrict__ cbuf,
                     unsigned short* __restrict__ h_all_bf,
                     int t)
{
    const int b = blockIdx.x, fc = blockIdx.y;
    const int tid = threadIdx.x;
    const int wave = tid >> 6, lane = tid & 63;
    __shared__ float ahT[8][64];
    __shared__ float awT[8][64];
    __shared__ float esm[kL];
    __shared__ float wsm[kL];
    __shared__ float red2[2];

    if (tid < kH) {
        const size_t base = (size_t)b * kNcat + 5 * kR + tid;
        float v = h2att_b[tid];
        #pragma unroll
        for (int s = 0; s < kKS; ++s) v += part56[(size_t)s * 64 * kNcat + base];
        ahT[tid & 7][tid >> 3] = v;
        awT[tid & 7][tid >> 3] = alpha_w[tid];
    }
    __syncthreads();

    // e: 8 waves, wave handles l = wave, wave+8, ...
    for (int l = wave; l < kL; l += 8) {
        const short8 pv = *(const short8*)(comb_bf + ((size_t)b * kL + l) * kNc2 + lane * 8);
        float a = 0.f;
        #pragma unroll
        for (int j = 0; j < 8; ++j)
            a += fast_tanh(bf2f(((const unsigned short*)&pv)[j]) + ahT[j][lane]) * awT[j][lane];
        #pragma unroll
        for (int off = 32; off; off >>= 1) a += __shfl_xor(a, off, 64);
        if (lane == 0) esm[l] = a;
    }
    __syncthreads();

    if (wave == 0) {
        float m = -1e30f;
        for (int l = lane; l < kL; l += 64) m = fmaxf(m, esm[l]);
        #pragma unroll
        for (int off = 32; off; off >>= 1) m = fmaxf(m, __shfl_xor(m, off, 64));
        float ssum = 0.f;
        for (int l = lane; l < kL; l += 64) ssum += __expf(esm[l] - m);
        #pragma unroll
        for (int off = 32; off; off >>= 1) ssum += __shfl_xor(ssum, off, 64);
        if (lane == 0) { red2[0] = m; red2[1] = 1.f / ssum; }
    }
    __syncthreads();
    if (tid < kL) wsm[tid] = __expf(esm[tid] - red2[0]) * red2[1];
    __syncthreads();

    // l-split interleaved readout: one ushort2 per l = (gate3, gate4)
    const int r = fc * 256 + (tid >> 1);
    const int l0 = (tid & 1) * 98;
    float s3 = 0.f, s4 = 0.f;
    const unsigned short* base = comb_bf + ((size_t)b * kL + l0) * kNc2 + kH + 2 * r;
    #pragma unroll 7
    for (int li = 0; li < 98; ++li) {
        const ushort2 v = *(const ushort2*)(base + (size_t)li * kNc2);
        const float wl = wsm[l0 + li];
        s3 += wl * bf2f(v.x);
        s4 += wl * bf2f(v.y);
    }
    s3 += __shfl_xor(s3, 1, 64);
    s4 += __shfl_xor(s4, 1, 64);

    if ((tid & 1) == 0) {
        const unsigned short* ib = i2h_pre_bf + (size_t)(b * kT + t) * (5 * kR);
        float S0 = bf2f(ib[r])          + h2h_b[r];
        float S1 = bf2f(ib[kR + r])     + h2h_b[kR + r];
        float S2 = bf2f(ib[2 * kR + r]) + h2h_b[2 * kR + r];
        float S3 = bf2f(ib[3 * kR + r]) + h2h_b[3 * kR + r] + s3;
        float S4 = bf2f(ib[4 * kR + r]) + h2h_b[4 * kR + r] + s4;
        #pragma unroll
        for (int s = 0; s < kKS; ++s) {
            const float* p = part56 + (size_t)s * 64 * kNcat + (size_t)b * kNcat;
            S0 += p[r];
            S1 += p[kR + r];
            S2 += p[2 * kR + r];
            S3 += p[3 * kR + r];
            S4 += p[4 * kR + r];
        }

        const float ing = fast_sig(S0);
        const float fg  = fast_sig(S1);
        const float og  = fast_sig(S2);
        const float gg  = fmaxf(S3, S4);
        const int idx = b * kR + r;
        const float nc = fg * cbuf[idx] + ing * gg;
        const float nh = og * fast_tanh(nc);
        cbuf[idx] = nc;
        h_all_bf[(size_t)(b * kT + t) * kR + r] = f2bf(nh);
    }
}

// ---------------------------------------------------------------------------
// in-place log_softmax over V; one block per row, 512 thr, float4 loads.
// ---------------------------------------------------------------------------
__global__ __launch_bounds__(512)
void log_softmax_kernel(float* __restrict__ out)
{
    __shared__ float mred[512];
    __shared__ float sred[512];
    const int tid = threadIdx.x;
    float* row = out + (size_t)blockIdx.x * kV;

    float m = -1e30f, s = 0.f;
    for (int g = tid; g < 3000; g += 512) {
        const float4 x4 = ((const float4*)row)[g];
        const float* x = (const float*)&x4;
        #pragma unroll
        for (int j = 0; j < 4; ++j) {
            const float x1 = x[j];
            if (x1 > m) { s = s * __expf(m - x1) + 1.f; m = x1; }
            else          s += __expf(x1 - m);
        }
    }
    if (tid == 0) {
        const float x1 = row[12000];
        if (x1 > m) { s = s * __expf(m - x1) + 1.f; m = x1; }
        else          s += __expf(x1 - m);
    }
    mred[tid] = m; sred[tid] = s; __syncthreads();
    for (int st = 256; st > 0; st >>= 1) {
        if (tid < st) {
            const float m2 = mred[tid + st], s2 = sred[tid + st];
            const float M = fmaxf(mred[tid], m2);
            sred[tid] = sred[tid] * __expf(mred[tid] - M) + s2 * __expf(m2 - M);
            mred[tid] = M;
        }
        __syncthreads();
    }
    const float ls = mred[0] + logf(sred[0]);
    for (int g = tid; g < 3000; g += 512) {
        float4 x4 = ((const float4*)row)[g];
        x4.x -= ls; x4.y -= ls; x4.z -= ls; x4.w -= ls;
        ((float4*)row)[g] = x4;
    }
    if (tid == 0) row[12000] -= ls;
}

extern "C" void kernel_launch(void* const* d_in, const int* in_sizes, int n_in,
                              void* d_out, int out_size, void* d_ws, size_t ws_size,
                              hipStream_t stream)
{
    const int*   seq       = (const int*)  d_in[0];
    const float* att_feats = (const float*)d_in[1];
    const float* embed_w   = (const float*)d_in[2];
    const float* ctx2att_w = (const float*)d_in[3];
    const float* ctx2att_b = (const float*)d_in[4];
    const float* h2att_w   = (const float*)d_in[5];
    const float* h2att_b   = (const float*)d_in[6];
    const float* alpha_w   = (const float*)d_in[7];
    const float* i2h_w     = (const float*)d_in[9];
    const float* i2h_b     = (const float*)d_in[10];
    const float* h2h_w     = (const float*)d_in[11];
    const float* h2h_b     = (const float*)d_in[12];
    const float* a2c_w     = (const float*)d_in[13];
    const float* a2c_b     = (const float*)d_in[14];
    const float* logit_w   = (const float*)d_in[15];
    const float* logit_b   = (const float*)d_in[16];
    float* out = (float*)d_out;

    float* ws = (float*)d_ws;
    size_t off = 0;
    auto alloc = [&](size_t nf) { float* p = ws + off; off += (nf + 3) & ~(size_t)3; return p; };

    unsigned short* af_bf      = (unsigned short*)alloc((size_t)kB * kL * kF / 2);   // 51 MB
    unsigned short* comb_bf    = (unsigned short*)alloc((size_t)kB * kL * kNc2 / 2); // 61.6 MB
    unsigned short* logit_hi   = (unsigned short*)alloc((size_t)kV * kR / 2);
    unsigned short* embed_bf   = (unsigned short*)alloc((size_t)kV * kEp / 2);
    unsigned short* i2h_bf     = (unsigned short*)alloc((size_t)5 * kR * kEp / 2);
    unsigned short* wcat_bf    = (unsigned short*)alloc((size_t)kNcat * kR / 2);     // 11.5 MB
    unsigned short* wcomb_bf   = (unsigned short*)alloc((size_t)kNc2 * kF / 2);      // 10.5 MB
    unsigned short* h_all_bf   = (unsigned short*)alloc((size_t)kB * kT * kR / 2);
    unsigned short* h_zero_bf  = (unsigned short*)alloc((size_t)kB * kR / 2);
    unsigned short* i2h_pre_bf = (unsigned short*)alloc((size_t)kB * kT * 5 * kR / 2); // 13 MB
    float* bias_comb = alloc((size_t)kNc2);
    float* part56    = alloc((size_t)kKS * kB * kNcat);  // 5.8 MB
    float* cbuf      = alloc((size_t)kB * kR);

    // all conversions + packs + zero-fills in ONE launch
    conv_all_kernel<<<4096, 256, 0, stream>>>(
        att_feats, af_bf, ctx2att_w, logit_w, logit_hi,
        h2h_w, wcat_bf, h2att_w, wcat_bf + (size_t)5 * kR * kR,
        a2c_w, wcomb_bf, embed_w, embed_bf, i2h_w, i2h_bf,
        h_zero_bf, cbuf, ctx2att_b, a2c_b, bias_comb);

    // comb = att_feats @ [ctx2att | a2c-interleaved].T + bias_comb -> bf16
    gemm_glds_kernel<true, false><<<dim3(20 * 98), 256, 0, stream>>>(
        af_bf, kF, wcomb_bf, kF, bias_comb, comb_bf, kNc2, kB * kL, kNc2, kF, nullptr,
        20, 98, 1);

    // i2h_pre = embed[seq] @ i2h_w.T + b -> bf16   (1280 x 5120, K=320 padded)
    gemm_glds_kernel<true, true><<<dim3(40 * 10), 256, 0, stream>>>(
        embed_bf, kEp, i2h_bf, kEp, i2h_b, i2h_pre_bf, 5 * kR, kB * kT, 5 * kR, kEp, seq,
        40, 10, 1);

    // 20-step recurrence: 2 launches per step
    for (int t = 0; t < kT; ++t) {
        const unsigned short* h_prev = (t == 0) ? h_zero_bf : (h_all_bf + (size_t)(t - 1) * kR);
        const int lda_h = (t == 0) ? kR : kT * kR;

        // part56 = h_prev @ [h2h | h2att].T   (64 x 5632, K=1024, ks=4)
        gemm_sums_kernel<<<dim3(kNcat / 64, kKS), 256, 0, stream>>>(
            h_prev, lda_h, wcat_bf, kR, part56, kNcat, kR / kKS);

        att_step_kernel<<<dim3(kB, 4), 512, 0, stream>>>(
            part56, h2att_b, comb_bf, alpha_w, i2h_pre_bf, h2h_b,
            cbuf, h_all_bf, t);
    }

    // logits = h_all @ logit_w.T + b -> out fp32  (1280 x 12001, K=1024)
    gemm_glds_kernel<false, false><<<dim3(94 * 10), 256, 0, stream>>>(
        h_all_bf, kR, logit_hi, kR, logit_b, out, kV, kB * kT, kV, kR, nullptr,
        94, 10, 0);

    log_softmax_kernel<<<dim3(kB * kT), 512, 0, stream>>>(out);
}